// Round 9
// baseline (333.303 us; speedup 1.0000x reference)
//
#include <hip/hip_runtime.h>

#define Rn 64
#define Hn 10
#define Fn 5

typedef float f32x2 __attribute__((ext_vector_type(2)));

#define PKFMA(a, b, c) __builtin_elementwise_fma((a), (b), (c))

// 8 lanes per batch: sub = (v<<2)|q, v = row-half (rows 5v..5v+4), q = gate
// lane (0:i 1:f 2:g 3:o). ALL weights live in VGPRs (f32x2 pairs) -- rounds
// 4/8 were LDS-return-bus-bound on per-lane weight re-reads (1MB/step/CU).
// Cross-lane: uniform shuffle choreography (no divergence); activation
// unified as B + A*rcp(exp(S*z)+1) with per-lane constants. x staged in
// wave-private LDS tiles (8 steps), one barrier per tile.
__global__ __launch_bounds__(256, 2) void seqreader_kernel(
    const float* __restrict__ r_emb, const float* __restrict__ feature,
    const float* __restrict__ h0, const float* __restrict__ c0,
    const float* __restrict__ W_ih, const float* __restrict__ W_hh,
    const float* __restrict__ b_ih, const float* __restrict__ b_hh,
    const float* __restrict__ Wr, const float* __restrict__ br,
    const float* __restrict__ Wh, const float* __restrict__ bh,
    const float* __restrict__ Wfc, const float* __restrict__ bfc,
    float* __restrict__ out)
{
    __shared__ f32x2 sX[2][32][41];   // [buf][batch-in-block][f2]; stride 41 f2 = 82 dw (8 groups -> distinct banks)
    __shared__ float sWfc[648];
    __shared__ float sWfcF[Fn + 1];

    const int tid  = threadIdx.x;
    const int lane = tid & 63;
    const int w    = tid >> 6;        // wave in block
    const int sub  = lane & 7;
    const int q    = sub & 3;         // gate lane
    const int v    = sub >> 2;        // row-half
    const int rr   = v * 5;           // row base
    const int bq   = tid >> 3;        // batch within block (0..31)
    const int b0   = blockIdx.x * 32;
    const int b    = b0 + bq;

    for (int i = tid; i < 645; i += 256) sWfc[i] = Wfc[i];
    if (tid < Fn) sWfcF[tid] = Wfc[Rn * Hn + tid];
    if (tid == Fn) sWfcF[Fn] = bfc[0];

    // ---- weights into VGPRs ----
    // gate weights: rows (q*10 + rr + j), 5 f2 pairs each (8B-aligned: row*10 even)
    f32x2 wih2[5][5], whh2[5][5];
#pragma unroll
    for (int j = 0; j < 5; ++j)
#pragma unroll
        for (int p = 0; p < 5; ++p) {
            const int row = q * 10 + rr + j;
            wih2[j][p] = *(const f32x2*)&W_ih[row * 10 + 2 * p];
            whh2[j][p] = *(const f32x2*)&W_hh[row * 10 + 2 * p];
        }
    // r-gate: q<2 -> Wr, q>=2 -> Wh; pb=0 (q even): pairs 0,1,2; pb=3 (q odd): pairs 3,4 (+zero)
    const bool hiP = (q & 1);
    const float* rsrc = (q < 2) ? Wr : Wh;
    f32x2 wr2[5][3];
#pragma unroll
    for (int j = 0; j < 5; ++j)
#pragma unroll
        for (int pp = 0; pp < 3; ++pp) {
            const int p = (hiP ? 3 : 0) + pp;
            wr2[j][pp] = (p < 5) ? *(const f32x2*)&rsrc[(rr + j) * 10 + 2 * p]
                                 : f32x2{0.f, 0.f};
        }

    float bz[5], brh[5];
#pragma unroll
    for (int j = 0; j < 5; ++j) {
        bz[j]  = b_ih[q * 10 + rr + j] + b_hh[q * 10 + rr + j];
        brh[j] = br[rr + j] + bh[rr + j];
    }

    // unified activation: a = actB + actA * rcp(exp(actS*z)+1)
    // sigma: S=-1,A=+1,B=0 ; tanh (q==2): S=+2,A=-2,B=+1
    const float actS = (q == 2) ?  2.f : -1.f;
    const float actA = (q == 2) ? -2.f :  1.f;
    const float actB = (q == 2) ?  1.f :  0.f;

    // state: c meaningful on q==1 lanes; h2 = full h (all lanes)
    float c[5];
#pragma unroll
    for (int j = 0; j < 5; ++j) c[j] = c0[(size_t)b * Hn + rr + j];
    f32x2 h2[5];
#pragma unroll
    for (int p = 0; p < 5; ++p) h2[p] = *(const f32x2*)&h0[(size_t)b * Hn + 2 * p];

    // ---- x staging maps (wave-private rows of sX) ----
    int lb_[5], e_[5];
#pragma unroll
    for (int k = 0; k < 5; ++k) {
        const int u = k * 64 + lane;
        lb_[k] = u / 40;          // local batch 0..7
        e_[k]  = u - lb_[k] * 40; // f2 elem 0..39 (8 steps x 5 f2)
    }
    const f32x2* gx = (const f32x2*)r_emb + (size_t)(b0 + w * 8) * (Rn * Hn / 2);

    f32x2 pf[5];
#pragma unroll
    for (int k = 0; k < 5; ++k) pf[k] = gx[(size_t)lb_[k] * 320 + e_[k]];
#pragma unroll
    for (int k = 0; k < 5; ++k) sX[0][w * 8 + lb_[k]][e_[k]] = pf[k];
    __syncthreads();

    float acc = 0.f;
    const int srcA = (lane & ~7) | 3;   // h_new rows 0-4 live on sub 3
    const int srcB = (lane & ~7) | 7;   // h_new rows 5-9 live on sub 7

#pragma unroll 1
    for (int G = 0; G < 8; ++G) {
        const int buf = G & 1;
        if (G < 7) {
#pragma unroll
            for (int k = 0; k < 5; ++k)
                pf[k] = gx[(size_t)lb_[k] * 320 + (G + 1) * 40 + e_[k]];
        }

#pragma unroll 1
        for (int s = 0; s < 8; ++s) {
            const int t = G * 8 + s;

            f32x2 x2[5];
#pragma unroll
            for (int p = 0; p < 5; ++p) x2[p] = sX[buf][bq][s * 5 + p];

            // own gate, own 5 rows
            float a[5];
#pragma unroll
            for (int j = 0; j < 5; ++j) {
                f32x2 zz = {bz[j], 0.f};
#pragma unroll
                for (int p = 0; p < 5; ++p) zz = PKFMA(wih2[j][p], x2[p], zz);
#pragma unroll
                for (int p = 0; p < 5; ++p) zz = PKFMA(whh2[j][p], h2[p], zz);
                const float z = zz[0] + zz[1];
                a[j] = fmaf(actA, __builtin_amdgcn_rcpf(__expf(actS * z) + 1.f), actB);
            }

            // cross-lane LSTM combine (uniform; only tagged lanes carry real data)
            float hn[5], tcn[5];
#pragma unroll
            for (int j = 0; j < 5; ++j) {
                const float t2 = __shfl_xor(a[j], 2, 64);       // lane0 <- tanh(g)
                const float p_ = a[j] * t2;                      // lane0: si*tg
                const float p1 = __shfl_xor(p_, 1, 64);          // lane1 <- si*tg
                c[j] = fmaf(a[j], c[j], p1);                     // lane1: sf*c + si*tg
                tcn[j] = 1.f - 2.f * __builtin_amdgcn_rcpf(__expf(2.f * c[j]) + 1.f);
            }
#pragma unroll
            for (int j = 0; j < 5; ++j) {
                const float t3 = __shfl_xor(tcn[j], 2, 64);      // lane3 <- tanh(c_new)
                hn[j] = a[j] * t3;                               // lane3: so*tanh(c_new)
            }

            // broadcast h_new to all 8 lanes of the batch group
            float hA[5], hB[5];
#pragma unroll
            for (int j = 0; j < 5; ++j) {
                hA[j] = __shfl(hn[j], srcA, 64);
                hB[j] = __shfl(hn[j], srcB, 64);
            }
            h2[0] = f32x2{hA[0], hA[1]};
            h2[1] = f32x2{hA[2], hA[3]};
            h2[2] = f32x2{hA[4], hB[0]};
            h2[3] = f32x2{hB[1], hB[2]};
            h2[4] = f32x2{hB[3], hB[4]};

            // mid-tile: write prefetched next tile (read next tile after barrier)
            if (s == 5 && G < 7) {
#pragma unroll
                for (int k = 0; k < 5; ++k)
                    sX[buf ^ 1][w * 8 + lb_[k]][e_[k]] = pf[k];
            }

            // r-gate: K split by pairs across q-lanes (Wr: q0 pairs 0-2, q1 pairs 3-4;
            // Wh: q2 pairs 0-2, q3 pairs 3-4), butterfly-summed
            const f32x2 s0 = (q < 2) ? x2[0] : h2[0];
            const f32x2 s1 = (q < 2) ? x2[1] : h2[1];
            const f32x2 s2 = (q < 2) ? x2[2] : h2[2];
            const f32x2 s3 = (q < 2) ? x2[3] : h2[3];
            const f32x2 s4 = (q < 2) ? x2[4] : h2[4];
            const f32x2 rin0 = hiP ? s3 : s0;
            const f32x2 rin1 = hiP ? s4 : s1;
            const f32x2 rin2 = s2;   // zero-weighted on hiP lanes

            float zr[5];
#pragma unroll
            for (int j = 0; j < 5; ++j) {
                f32x2 zz = {0.f, 0.f};
                zz = PKFMA(wr2[j][0], rin0, zz);
                zz = PKFMA(wr2[j][1], rin1, zz);
                zz = PKFMA(wr2[j][2], rin2, zz);
                zr[j] = zz[0] + zz[1];
            }
#pragma unroll
            for (int j = 0; j < 5; ++j) zr[j] += __shfl_xor(zr[j], 1, 64);
#pragma unroll
            for (int j = 0; j < 5; ++j) zr[j] += __shfl_xor(zr[j], 2, 64);

#pragma unroll
            for (int j = 0; j < 5; ++j) {
                const float rg = __builtin_amdgcn_rcpf(__expf(-(zr[j] + brh[j])) + 1.f);
                const float hv = v ? hB[j] : hA[j];
                acc = fmaf(hv * rg, sWfc[t * Hn + rr + j], acc);
            }
        }
        __syncthreads();
    }

    // combine row-halves; one lane per batch writes
    acc += __shfl_xor(acc, 4, 64);
    if (sub == 0) {
        float sres = acc + sWfcF[Fn];
#pragma unroll
        for (int k = 0; k < Fn; ++k)
            sres = fmaf(feature[(size_t)b * Fn + k], sWfcF[k], sres);
        out[b] = sres;
    }
}

extern "C" void kernel_launch(void* const* d_in, const int* in_sizes, int n_in,
                              void* d_out, int out_size, void* d_ws, size_t ws_size,
                              hipStream_t stream) {
    const float* r_emb   = (const float*)d_in[0];
    const float* feature = (const float*)d_in[1];
    const float* h0      = (const float*)d_in[2];
    const float* c0      = (const float*)d_in[3];
    const float* W_ih    = (const float*)d_in[4];
    const float* W_hh    = (const float*)d_in[5];
    const float* b_ih    = (const float*)d_in[6];
    const float* b_hh    = (const float*)d_in[7];
    const float* Wr      = (const float*)d_in[8];
    const float* br      = (const float*)d_in[9];
    const float* Wh      = (const float*)d_in[10];
    const float* bh      = (const float*)d_in[11];
    const float* Wfc     = (const float*)d_in[12];
    const float* bfc     = (const float*)d_in[13];
    float* out = (float*)d_out;

    dim3 grid(65536 / 32), block(256);
    hipLaunchKernelGGL(seqreader_kernel, grid, block, 0, stream,
                       r_emb, feature, h0, c0, W_ih, W_hh, b_ih, b_hh,
                       Wr, br, Wh, bh, Wfc, bfc, out);
}

// Round 10
// 211.549 us; speedup vs baseline: 1.5755x; 1.5755x over previous
//
#include <hip/hip_runtime.h>

#define Rn 64
#define Hn 10
#define Fn 5
#define XRS 52   // x-tile row stride in dwords (4 steps x 12, +4 pad; 208B = 16B-aligned)

typedef float f32x2 __attribute__((ext_vector_type(2)));
typedef float f32x4 __attribute__((ext_vector_type(4)));

#define PKFMA(a, b, c) __builtin_elementwise_fma((a), (b), (c))

__device__ __forceinline__ float fsigmoid(float x) {
    return __builtin_amdgcn_rcpf(1.0f + __expf(-x));
}
__device__ __forceinline__ float ftanh(float x) {
    return 1.0f - 2.0f * __builtin_amdgcn_rcpf(__expf(2.0f * x) + 1.0f);
}

// Round-8 structure (2 lanes/batch via shfl_xor(32), pkFMA math) with the DS
// instruction count cut 3.3x: weight rows (stride 12) read as 3x ds_read_b128,
// x-tile re-laid out so each step's 10 floats start 16B-aligned (3x b128).
// Rounds 4/8 were DS-pipe ISSUE-bound (~250 reads/lane/step x 8 waves ~ 9k
// cy/step); this brings it to ~153 b128/lane/step.
__global__ __launch_bounds__(256, 2) void seqreader_kernel(
    const float* __restrict__ r_emb,
    const float* __restrict__ feature,
    const float* __restrict__ h0,
    const float* __restrict__ c0,
    const float* __restrict__ W_ih,
    const float* __restrict__ W_hh,
    const float* __restrict__ b_ih,
    const float* __restrict__ b_hh,
    const float* __restrict__ Wr,
    const float* __restrict__ br,
    const float* __restrict__ Wh,
    const float* __restrict__ bh,
    const float* __restrict__ Wfc,
    const float* __restrict__ bfc,
    float* __restrict__ out)
{
    __shared__ __align__(16) float sWih[40 * 12];
    __shared__ __align__(16) float sWhh[40 * 12];
    __shared__ __align__(16) float sWr[10 * 12];
    __shared__ __align__(16) float sWhn[10 * 12];
    __shared__ float sWfc[646];
    __shared__ __align__(16) float sX[2][128 * XRS];

    const int tid  = threadIdx.x;
    const int lane = tid & 63;
    const int half = lane >> 5;        // 0: rows 0-4, 1: rows 5-9
    const int r0h  = half * 5;
    const int bb   = (tid >> 6) * 32 + (lane & 31);  // batch within block
    const int b0   = blockIdx.x * 128;
    const int b    = b0 + bb;

    for (int i = tid; i < 400; i += 256) {
        int r = i / 10, k = i - r * 10;
        sWih[r * 12 + k] = W_ih[i];
        sWhh[r * 12 + k] = W_hh[i];
    }
    for (int i = tid; i < 100; i += 256) {
        int r = i / 10, k = i - r * 10;
        sWr[r * 12 + k]  = Wr[i];
        sWhn[r * 12 + k] = Wh[i];
    }
    for (int i = tid; i < 645; i += 256) sWfc[i] = Wfc[i];

    float bi[5], bf_[5], bg_[5], bo[5], brh[5];
#pragma unroll
    for (int j = 0; j < 5; ++j) {
        bi[j]  = b_ih[0  + r0h + j] + b_hh[0  + r0h + j];
        bf_[j] = b_ih[10 + r0h + j] + b_hh[10 + r0h + j];
        bg_[j] = b_ih[20 + r0h + j] + b_hh[20 + r0h + j];
        bo[j]  = b_ih[30 + r0h + j] + b_hh[30 + r0h + j];
        brh[j] = br[r0h + j] + bh[r0h + j];
    }

    float c[5];
#pragma unroll
    for (int j = 0; j < 5; ++j) c[j] = c0[b * Hn + r0h + j];
    float hf[Hn];
#pragma unroll
    for (int k = 0; k < Hn; ++k) hf[k] = h0[b * Hn + k];

    float acc = 0.0f;
    if (half == 0) {
        acc = bfc[0];
#pragma unroll
        for (int k = 0; k < Fn; ++k)
            acc = fmaf(feature[b * Fn + k], Wfc[Rn * Hn + k], acc);
    }

    // gather map: tile = 128 batches x 40 floats = 1280 float4; 5 per thread.
    // dest: batch row stride XRS dwords, step sub-stride 12 (16B-aligned).
    unsigned off_g[5], off_l[5][4];
#pragma unroll
    for (int k = 0; k < 5; ++k) {
        int q  = k * 256 + tid;
        int bq = q / 10;
        int e  = q - bq * 10;
        off_g[k] = (unsigned)((bq * (Rn * Hn) + e * 4) * 4);  // bytes
#pragma unroll
        for (int cidx = 0; cidx < 4; ++cidx) {
            int u = e * 4 + cidx;            // element 0..39 within batch-tile
            int s = u / 10, kk = u - s * 10; // step-in-tile, k
            off_l[k][cidx] = (unsigned)(bq * XRS + s * 12 + kk);
        }
    }
    const char* gb = (const char*)(r_emb + (size_t)b0 * (Rn * Hn));

    // stage tile 0
    {
        float4 s0[5];
#pragma unroll
        for (int k = 0; k < 5; ++k) s0[k] = *(const float4*)(gb + off_g[k]);
#pragma unroll
        for (int k = 0; k < 5; ++k) {
            sX[0][off_l[k][0]] = s0[k].x;
            sX[0][off_l[k][1]] = s0[k].y;
            sX[0][off_l[k][2]] = s0[k].z;
            sX[0][off_l[k][3]] = s0[k].w;
        }
    }
    __syncthreads();

    float4 st[5];
#pragma unroll 1
    for (int t = 0; t < Rn; ++t) {
        const int tt = t & 3;
        const int Tb = (t >> 2) & 1;

        if (tt == 0 && t + 4 < Rn) {
#pragma unroll
            for (int k = 0; k < 5; ++k)
                st[k] = *(const float4*)(gb + off_g[k] + (unsigned)(t / 4 + 1) * 160u);
        }

        // x_t: 3x b128 (k0-3, k4-7, k8-9+pad)
        const f32x4* xr = (const f32x4*)&sX[Tb][bb * XRS + tt * 12];
        const f32x4 xq0 = xr[0], xq1 = xr[1], xq2 = xr[2];
        const f32x2 x01 = xq0.lo, x23 = xq0.hi, x45 = xq1.lo, x67 = xq1.hi, x89 = xq2.lo;

        f32x2 h2[5];
#pragma unroll
        for (int p = 0; p < 5; ++p) h2[p] = f32x2{hf[2 * p], hf[2 * p + 1]};

        // own half of the LSTM cell (5 rows, all 4 gates): b128 weight reads
        float hn[5];
#pragma unroll
        for (int j = 0; j < 5; ++j) {
            float zg[4];
#pragma unroll
            for (int gidx = 0; gidx < 4; ++gidx) {
                const int row = gidx * 10 + r0h + j;
                const f32x4* wi = (const f32x4*)&sWih[row * 12];
                const f32x4* wh = (const f32x4*)&sWhh[row * 12];
                const f32x4 wi0 = wi[0], wi1 = wi[1], wi2 = wi[2];
                const f32x4 wh0 = wh[0], wh1 = wh[1], wh2 = wh[2];
                f32x2 z2 = {0.f, 0.f};
                z2 = PKFMA(wi0.lo, x01, z2);
                z2 = PKFMA(wi0.hi, x23, z2);
                z2 = PKFMA(wi1.lo, x45, z2);
                z2 = PKFMA(wi1.hi, x67, z2);
                z2 = PKFMA(wi2.lo, x89, z2);
                z2 = PKFMA(wh0.lo, h2[0], z2);
                z2 = PKFMA(wh0.hi, h2[1], z2);
                z2 = PKFMA(wh1.lo, h2[2], z2);
                z2 = PKFMA(wh1.hi, h2[3], z2);
                z2 = PKFMA(wh2.lo, h2[4], z2);
                zg[gidx] = z2[0] + z2[1];
            }
            const float si = fsigmoid(zg[0] + bi[j]);
            const float sf = fsigmoid(zg[1] + bf_[j]);
            const float tg = ftanh(zg[2] + bg_[j]);
            const float so = fsigmoid(zg[3] + bo[j]);
            const float cn = fmaf(sf, c[j], si * tg);
            c[j] = cn;
            hn[j] = so * ftanh(cn);
        }

        // exchange halves in-wave: partner lane = lane ^ 32
        float sw[5];
#pragma unroll
        for (int j = 0; j < 5; ++j) sw[j] = __shfl_xor(hn[j], 32, 64);
#pragma unroll
        for (int j = 0; j < 5; ++j) {
            hf[j]     = half ? sw[j] : hn[j];
            hf[5 + j] = half ? hn[j] : sw[j];
        }

        // write next x tile into the other buffer (prefetched at tt==0)
        if (tt == 2 && t + 2 < Rn) {
#pragma unroll
            for (int k = 0; k < 5; ++k) {
                sX[Tb ^ 1][off_l[k][0]] = st[k].x;
                sX[Tb ^ 1][off_l[k][1]] = st[k].y;
                sX[Tb ^ 1][off_l[k][2]] = st[k].z;
                sX[Tb ^ 1][off_l[k][3]] = st[k].w;
            }
        }

        // r-gate + fused FC accumulation (own rows): b128 weight reads
        f32x2 hn2[5];
#pragma unroll
        for (int p = 0; p < 5; ++p) hn2[p] = f32x2{hf[2 * p], hf[2 * p + 1]};
#pragma unroll
        for (int j = 0; j < 5; ++j) {
            const int row = r0h + j;
            const f32x4* wr_ = (const f32x4*)&sWr[row * 12];
            const f32x4* wh_ = (const f32x4*)&sWhn[row * 12];
            const f32x4 wr0 = wr_[0], wr1 = wr_[1], wr2 = wr_[2];
            const f32x4 wh0 = wh_[0], wh1 = wh_[1], wh2 = wh_[2];
            f32x2 z2 = {0.f, 0.f};
            z2 = PKFMA(wr0.lo, x01, z2);
            z2 = PKFMA(wr0.hi, x23, z2);
            z2 = PKFMA(wr1.lo, x45, z2);
            z2 = PKFMA(wr1.hi, x67, z2);
            z2 = PKFMA(wr2.lo, x89, z2);
            z2 = PKFMA(wh0.lo, hn2[0], z2);
            z2 = PKFMA(wh0.hi, hn2[1], z2);
            z2 = PKFMA(wh1.lo, hn2[2], z2);
            z2 = PKFMA(wh1.hi, hn2[3], z2);
            z2 = PKFMA(wh2.lo, hn2[4], z2);
            const float s = z2[0] + z2[1] + brh[j];
            acc = fmaf(hn[j] * fsigmoid(s), sWfc[t * Hn + r0h + j], acc);
        }

        if (tt == 3) __syncthreads();
    }

    // combine the two lane-halves' partial FC sums; half 0 writes
    acc += __shfl_xor(acc, 32, 64);
    if (half == 0) out[b] = acc;
}

extern "C" void kernel_launch(void* const* d_in, const int* in_sizes, int n_in,
                              void* d_out, int out_size, void* d_ws, size_t ws_size,
                              hipStream_t stream) {
    const float* r_emb   = (const float*)d_in[0];
    const float* feature = (const float*)d_in[1];
    const float* h0      = (const float*)d_in[2];
    const float* c0      = (const float*)d_in[3];
    const float* W_ih    = (const float*)d_in[4];
    const float* W_hh    = (const float*)d_in[5];
    const float* b_ih    = (const float*)d_in[6];
    const float* b_hh    = (const float*)d_in[7];
    const float* Wr      = (const float*)d_in[8];
    const float* br      = (const float*)d_in[9];
    const float* Wh      = (const float*)d_in[10];
    const float* bh      = (const float*)d_in[11];
    const float* Wfc     = (const float*)d_in[12];
    const float* bfc     = (const float*)d_in[13];
    float* out = (float*)d_out;

    dim3 grid(65536 / 128), block(256);
    hipLaunchKernelGGL(seqreader_kernel, grid, block, 0, stream,
                       r_emb, feature, h0, c0, W_ih, W_hh, b_ih, b_hh,
                       Wr, br, Wh, bh, Wfc, bfc, out);
}